// Round 3
// baseline (183.478 us; speedup 1.0000x reference)
//
#include <hip/hip_runtime.h>
#include <hip/hip_bf16.h>

// out[b,a,x,y] = -C0 * sum_{s,r} s[b,s,x,y] * L[s,r,a] * Fn[b,r,x,y]
// Fn = periodic 4-neighbor sum of s over the (x,y) lattice.
// Shapes: s (32,3,512,512) f32, t scalar (unused), C0 scalar, L (3,3,3) f32.

constexpr int B = 32, X = 512, Y = 512;
constexpr int XY = X * Y;

typedef float v4f __attribute__((ext_vector_type(4)));  // native vector: OK for nontemporal builtins

__global__ __launch_bounds__(256)
void psi0_kernel(const float* __restrict__ s,
                 const float* __restrict__ C0p,
                 const float* __restrict__ Lp,
                 float* __restrict__ out)
{
    __shared__ float Ls[27];
    if (threadIdx.x < 27) Ls[threadIdx.x] = Lp[threadIdx.x];
    __syncthreads();

    const int tid  = threadIdx.x;
    const int lane = tid & 63;           // wave lane
    const int ty   = tid & 127;          // 128 threads cover one x-row (512/4)
    const int row  = tid >> 7;           // 2 rows per block

    // XCD-contiguous swizzle: consecutive blockIdx round-robin over 8 XCDs,
    // so give XCD k the contiguous strip range [k*per, (k+1)*per) — adjacent-x
    // blocks (which share stencil rows) then hit the same XCD L2.
    const int per = gridDim.x >> 3;                       // 8192/8 = 1024
    const int sw  = (blockIdx.x & 7) * per + (blockIdx.x >> 3);

    const int b  = sw >> 8;              // 256 row-pairs per batch
    const int x  = ((sw & 255) << 1) + row;
    const int y0 = ty << 2;

    const int xm = (x == 0)     ? X - 1 : x - 1;
    const int xp = (x == X - 1) ? 0     : x + 1;
    const int ym = (y0 == 0)     ? Y - 1 : y0 - 1;  // wrap for left edge
    const int yp = (y0 + 4 == Y) ? 0     : y0 + 4;  // wrap for right edge

    const size_t baseB = (size_t)b * 3 * XY;
    const float* p0 = s + baseB;
    const size_t rc = (size_t)x  * Y + y0;
    const size_t ru = (size_t)xm * Y + y0;
    const size_t rd = (size_t)xp * Y + y0;

    // ---- load phase: all 9 float4 loads issued before any use (max MLP) ----
    v4f ce[3], up[3], dn[3];
    #pragma unroll
    for (int c = 0; c < 3; ++c) {
        const float* p = p0 + (size_t)c * XY;
        ce[c] = *(const v4f*)(p + rc);
        up[c] = *(const v4f*)(p + ru);
        dn[c] = *(const v4f*)(p + rd);
    }

    // y-edge neighbors via intra-wave shuffle of the center row (all lanes of
    // a wave share one x-row); only lane 0 / lane 63 need a 1-lane fallback.
    float lf[3], rt[3];
    #pragma unroll
    for (int c = 0; c < 3; ++c) {
        lf[c] = __shfl_up(ce[c].w, 1);
        rt[c] = __shfl_down(ce[c].x, 1);
    }
    if (lane == 0) {
        #pragma unroll
        for (int c = 0; c < 3; ++c) lf[c] = p0[(size_t)c * XY + (size_t)x * Y + ym];
    }
    if (lane == 63) {
        #pragma unroll
        for (int c = 0; c < 3; ++c) rt[c] = p0[(size_t)c * XY + (size_t)x * Y + yp];
    }

    // ---- stencil sum ----
    v4f Fn[3];
    #pragma unroll
    for (int c = 0; c < 3; ++c) {
        Fn[c].x = up[c].x + dn[c].x + lf[c]   + ce[c].y;
        Fn[c].y = up[c].y + dn[c].y + ce[c].x + ce[c].z;
        Fn[c].z = up[c].z + dn[c].z + ce[c].y + ce[c].w;
        Fn[c].w = up[c].w + dn[c].w + ce[c].z + rt[c];
    }

    // ---- contraction with L + nontemporal streaming store ----
    const float nC0 = -C0p[0];
    #pragma unroll
    for (int a = 0; a < 3; ++a) {
        v4f acc = (v4f)0.f;
        #pragma unroll
        for (int ss = 0; ss < 3; ++ss) {
            #pragma unroll
            for (int r = 0; r < 3; ++r) {
                const float w = Ls[ss * 9 + r * 3 + a];
                acc += w * ce[ss] * Fn[r];
            }
        }
        v4f o = nC0 * acc;
        __builtin_nontemporal_store(o, (v4f*)(out + baseB + (size_t)a * XY + rc));
    }
}

extern "C" void kernel_launch(void* const* d_in, const int* in_sizes, int n_in,
                              void* d_out, int out_size, void* d_ws, size_t ws_size,
                              hipStream_t stream)
{
    const float* s   = (const float*)d_in[0];
    // d_in[1] = t (unused: coeff is t-independent with a single cc entry)
    const float* C0p = (const float*)d_in[2];
    const float* Lp  = (const float*)d_in[3];
    float* out = (float*)d_out;

    const int blocks = B * (X / 2);   // 8192 blocks, 256 threads = 2 x-rows each
    psi0_kernel<<<blocks, 256, 0, stream>>>(s, C0p, Lp, out);
}